// Round 7
// baseline (444.869 us; speedup 1.0000x reference)
//
#include <hip/hip_runtime.h>
#include <hip/hip_bf16.h>

#define N_NODES 100000
#define N_EDGES 600000
#define D 128
#define NG_E 12   // 16-edge groups per block: 600000/(16*12) = 3125 blocks
#define NG_N 10   // 16-row  groups per block: 100000/(16*10) = 625 blocks
#define SCAN_B 512
#define NBLK ((N_NODES + SCAN_B - 1) / SCAN_B)   // 196

typedef __attribute__((ext_vector_type(8))) short short8;
typedef __attribute__((ext_vector_type(8))) unsigned short ushort8;
typedef __attribute__((ext_vector_type(4))) unsigned int uint4v;
typedef __attribute__((ext_vector_type(4))) float f32x4;

union V8 { short8 s8; ushort8 u8; uint4v u4; };

__device__ __forceinline__ unsigned short f2bf(float f) {
    unsigned u = __float_as_uint(f);
    u += 0x7FFF + ((u >> 16) & 1);   // RNE
    return (unsigned short)(u >> 16);
}

// ---------------- weight fragment + bf16 conversion ----------------
__global__ void wfrag_kernel(const float* __restrict__ Wi,
                             const float* __restrict__ We,
                             unsigned short* __restrict__ Wfi,
                             unsigned short* __restrict__ Wfe) {
    int id = blockIdx.x * blockDim.x + threadIdx.x;   // 0..4095
    int mat = id >> 11;
    int idx = id & 2047;          // nt<<8 | ks<<6 | lane
    int lane = idx & 63;
    int ks = (idx >> 6) & 3;
    int nt = idx >> 8;
    int n = lane & 15, quad = lane >> 4;
    int row = nt * 16 + n;
    int k0 = ks * 32 + quad * 8;
    const float* W = mat ? We : Wi;
    unsigned short* Wf = mat ? Wfe : Wfi;
    #pragma unroll
    for (int j = 0; j < 8; ++j)
        Wf[idx * 8 + j] = f2bf(W[row * D + k0 + j]);
}

__global__ void cvt2_kernel(const float* __restrict__ a,
                            const float* __restrict__ b,
                            unsigned short* __restrict__ ab,
                            unsigned short* __restrict__ bb, int n4) {
    int i = blockIdx.x * blockDim.x + threadIdx.x;
    const float4* src;
    ushort4* dst;
    int j;
    if (i < n4) {
        j = i; src = (const float4*)a; dst = (ushort4*)ab;
    } else if (i < 2 * n4) {
        j = i - n4; src = (const float4*)b; dst = (ushort4*)bb;
    } else return;
    float4 v = src[j];
    ushort4 o;
    o.x = f2bf(v.x); o.y = f2bf(v.y); o.z = f2bf(v.z); o.w = f2bf(v.w);
    dst[j] = o;
}

// ---------------- dst-sort preprocessing (CSR order) ----------------
__global__ void hist_kernel(const int* __restrict__ dst_idx,
                            unsigned* __restrict__ cnt) {
    int i = blockIdx.x * blockDim.x + threadIdx.x;
    if (i < N_EDGES) atomicAdd(&cnt[dst_idx[i]], 1u);
}

// per-block exclusive scan of cnt -> off, block totals -> bsum
__global__ __launch_bounds__(SCAN_B) void scanA_kernel(
    const unsigned* __restrict__ cnt, unsigned* __restrict__ off,
    unsigned* __restrict__ bsum) {
    int b = blockIdx.x, t = threadIdx.x;
    int i = b * SCAN_B + t;
    unsigned x = (i < N_NODES) ? cnt[i] : 0u;
    unsigned v = x;
    #pragma unroll
    for (int o = 1; o < 64; o <<= 1) {
        unsigned u = __shfl_up(v, o);
        if ((t & 63) >= o) v += u;
    }
    __shared__ unsigned wsum[SCAN_B / 64];
    if ((t & 63) == 63) wsum[t >> 6] = v;
    __syncthreads();
    if (t < SCAN_B / 64) {
        unsigned s = wsum[t];
        unsigned vv = s;
        #pragma unroll
        for (int o = 1; o < SCAN_B / 64; o <<= 1) {
            unsigned u = __shfl_up(vv, o);
            if (t >= o) vv += u;
        }
        wsum[t] = vv - s;   // exclusive wave offset
    }
    __syncthreads();
    unsigned inc = v + wsum[t >> 6];
    if (i < N_NODES) off[i] = inc - x;   // exclusive
    if (t == SCAN_B - 1) bsum[b] = inc;
}

// single block: exclusive scan of bsum (NBLK <= 256)
__global__ __launch_bounds__(256) void scanB_kernel(unsigned* __restrict__ bsum) {
    int t = threadIdx.x;
    unsigned x = (t < NBLK) ? bsum[t] : 0u;
    unsigned v = x;
    #pragma unroll
    for (int o = 1; o < 64; o <<= 1) {
        unsigned u = __shfl_up(v, o);
        if ((t & 63) >= o) v += u;
    }
    __shared__ unsigned wsum[4];
    if ((t & 63) == 63) wsum[t >> 6] = v;
    __syncthreads();
    if (t < 4) {
        unsigned s = wsum[t];
        unsigned vv = s;
        #pragma unroll
        for (int o = 1; o < 4; o <<= 1) {
            unsigned u = __shfl_up(vv, o);
            if (t >= o) vv += u;
        }
        wsum[t] = vv - s;
    }
    __syncthreads();
    unsigned inc = v + wsum[t >> 6];
    if (t < NBLK) bsum[t] = inc - x;   // exclusive
}

__global__ void scanC_kernel(unsigned* __restrict__ off,
                             const unsigned* __restrict__ bsum) {
    int i = blockIdx.x * blockDim.x + threadIdx.x;
    if (i < N_NODES) off[i] += bsum[i / SCAN_B];
}

// scatter edges into dst-sorted order; destroys off (used as cursor)
__global__ void scatter_kernel(const int* __restrict__ src_idx,
                               const int* __restrict__ dst_idx,
                               const float* __restrict__ ew,
                               unsigned* __restrict__ off,
                               int* __restrict__ sIp, int* __restrict__ dIp,
                               float* __restrict__ ewp) {
    int i = blockIdx.x * blockDim.x + threadIdx.x;
    if (i < N_EDGES) {
        int d = dst_idx[i];
        unsigned pos = atomicAdd(&off[d], 1u);
        sIp[pos] = src_idx[i];
        dIp[pos] = d;
        ewp[pos] = ew[i];
    }
}

// ---------------- node self-message ----------------
__global__ __launch_bounds__(256, 4) void node_mfma2_kernel(
    const unsigned short* __restrict__ dst_bf,
    const unsigned short* __restrict__ Wfi, float* __restrict__ out) {
    int t = threadIdx.x, lane = t & 63, w = t >> 6;
    int quad = lane >> 4, nl = lane & 15;
    const short8* Wv = (const short8*)Wfi;
    short8 Bf[2][4];
    #pragma unroll
    for (int ntl = 0; ntl < 2; ++ntl)
        #pragma unroll
        for (int ks = 0; ks < 4; ++ks)
            Bf[ntl][ks] = Wv[((2 * w + ntl) * 4 + ks) * 64 + lane];

    int base = blockIdx.x * (NG_N * 16);
    for (int g = 0; g < NG_N; ++g) {
        int gbase = base + g * 16;
        const unsigned short* xr = dst_bf + (size_t)(gbase + nl) * D + quad * 8;
        f32x4 acc[2];
        acc[0] = (f32x4){0.f, 0.f, 0.f, 0.f};
        acc[1] = (f32x4){0.f, 0.f, 0.f, 0.f};
        #pragma unroll
        for (int ks = 0; ks < 4; ++ks) {
            short8 a = *(const short8*)(xr + ks * 32);
            acc[0] = __builtin_amdgcn_mfma_f32_16x16x32_bf16(a, Bf[0][ks], acc[0], 0, 0, 0);
            acc[1] = __builtin_amdgcn_mfma_f32_16x16x32_bf16(a, Bf[1][ks], acc[1], 0, 0, 0);
        }
        #pragma unroll
        for (int ntl = 0; ntl < 2; ++ntl)
            #pragma unroll
            for (int r = 0; r < 4; ++r)
                out[(size_t)(gbase + quad * 4 + r) * D + (2 * w + ntl) * 16 + nl]
                    = acc[ntl][r];
    }
}

// ---------------- fused edge GEMM over dst-sorted edges ----------------
// msg = ew*(src@Wi^T + (src*dst)@We^T); sorted dst -> in-register segmented
// reduction over each quad's 4 rows before atomics.
__global__ __launch_bounds__(256, 2) void edge_mfma4_kernel(
    const unsigned short* __restrict__ src_bf,
    const unsigned short* __restrict__ dst_bf,
    const int* __restrict__ sIp, const int* __restrict__ dIp,
    const float* __restrict__ ewp,
    const unsigned short* __restrict__ Wfi,
    const unsigned short* __restrict__ Wfe,
    float* __restrict__ out) {
    int t = threadIdx.x, lane = t & 63, w = t >> 6;
    int quad = lane >> 4, nl = lane & 15;
    const short8* Wiv = (const short8*)Wfi;
    const short8* Wev = (const short8*)Wfe;
    short8 Bi[2][4], Be[2][4];
    #pragma unroll
    for (int ntl = 0; ntl < 2; ++ntl)
        #pragma unroll
        for (int ks = 0; ks < 4; ++ks) {
            Bi[ntl][ks] = Wiv[((2 * w + ntl) * 4 + ks) * 64 + lane];
            Be[ntl][ks] = Wev[((2 * w + ntl) * 4 + ks) * 64 + lane];
        }

    int base = blockIdx.x * (NG_E * 16);

    int sC = sIp[base + lane];
    int dC = dIp[base + lane];
    float eC = ewp[base + lane];

    V8 sv[2][4], dv[2][4];

    {   // prefetch group 0
        int sl = __shfl(sC, nl);
        int tl = __shfl(dC, nl);
        const unsigned short* sp = src_bf + (size_t)sl * D + quad * 8;
        const unsigned short* dp = dst_bf + (size_t)tl * D + quad * 8;
        #pragma unroll
        for (int ks = 0; ks < 4; ++ks) {
            sv[0][ks].u8 = *(const ushort8*)(sp + ks * 32);
            dv[0][ks].u8 = *(const ushort8*)(dp + ks * 32);
        }
    }

    #pragma unroll
    for (int g = 0; g < NG_E; ++g) {
        const int buf = g & 1, nbuf = buf ^ 1;
        int sN = sC, dN = dC;
        float eN = eC;
        bool roll = false;

        if (g + 1 < NG_E) {
            const int gn = g + 1;
            if ((gn & 3) == 0) {
                int cb = base + gn * 16;
                sN = sIp[cb + lane];
                dN = dIp[cb + lane];
                eN = ewp[cb + lane];
                roll = true;
            }
            const int gi = gn & 3;
            int sl = __shfl(roll ? sN : sC, gi * 16 + nl);
            int tl = __shfl(roll ? dN : dC, gi * 16 + nl);
            const unsigned short* sp = src_bf + (size_t)sl * D + quad * 8;
            const unsigned short* dp = dst_bf + (size_t)tl * D + quad * 8;
            #pragma unroll
            for (int ks = 0; ks < 4; ++ks) {
                sv[nbuf][ks].u8 = *(const ushort8*)(sp + ks * 32);
                dv[nbuf][ks].u8 = *(const ushort8*)(dp + ks * 32);
            }
        }

        f32x4 acc[2];
        acc[0] = (f32x4){0.f, 0.f, 0.f, 0.f};
        acc[1] = (f32x4){0.f, 0.f, 0.f, 0.f};
        #pragma unroll
        for (int ks = 0; ks < 4; ++ks) {
            V8 pU;
            #pragma unroll
            for (int h = 0; h < 4; ++h) {
                unsigned su = sv[buf][ks].u4[h], du = dv[buf][ks].u4[h];
                float p0 = __uint_as_float(su << 16) * __uint_as_float(du << 16);
                float p1 = __uint_as_float(su & 0xFFFF0000u) *
                           __uint_as_float(du & 0xFFFF0000u);
                __hip_bfloat162 h2 = __float22bfloat162_rn(make_float2(p0, p1));
                pU.u4[h] = *(unsigned*)&h2;
            }
            short8 a1 = sv[buf][ks].s8, a2 = pU.s8;
            acc[0] = __builtin_amdgcn_mfma_f32_16x16x32_bf16(a1, Bi[0][ks], acc[0], 0, 0, 0);
            acc[1] = __builtin_amdgcn_mfma_f32_16x16x32_bf16(a1, Bi[1][ks], acc[1], 0, 0, 0);
            acc[0] = __builtin_amdgcn_mfma_f32_16x16x32_bf16(a2, Be[0][ks], acc[0], 0, 0, 0);
            acc[1] = __builtin_amdgcn_mfma_f32_16x16x32_bf16(a2, Be[1][ks], acc[1], 0, 0, 0);
        }

        // epilogue: segmented reduction over this quad's 4 sorted rows
        const int gi = g & 3;
        int dr[4]; float wm[4];
        #pragma unroll
        for (int r = 0; r < 4; ++r) {
            int sl = gi * 16 + quad * 4 + r;
            dr[r] = __shfl(dC, sl);
            wm[r] = __shfl(eC, sl);
        }
        float run0 = wm[0] * acc[0][0];
        float run1 = wm[0] * acc[1][0];
        #pragma unroll
        for (int r = 1; r < 4; ++r) {
            if (dr[r] == dr[r - 1]) {
                run0 += wm[r] * acc[0][r];
                run1 += wm[r] * acc[1][r];
            } else {
                float* orow = out + (size_t)dr[r - 1] * D;
                atomicAdd(orow + (2 * w) * 16 + nl, run0);
                atomicAdd(orow + (2 * w + 1) * 16 + nl, run1);
                run0 = wm[r] * acc[0][r];
                run1 = wm[r] * acc[1][r];
            }
        }
        float* orow = out + (size_t)dr[3] * D;
        atomicAdd(orow + (2 * w) * 16 + nl, run0);
        atomicAdd(orow + (2 * w + 1) * 16 + nl, run1);

        if (roll) { sC = sN; dC = dN; eC = eN; }
    }
}

__global__ void leaky_relu4_kernel(float* __restrict__ out, int n4) {
    int i = blockIdx.x * blockDim.x + threadIdx.x;
    if (i < n4) {
        float4 v = ((const float4*)out)[i];
        v.x = v.x > 0.f ? v.x : 0.01f * v.x;
        v.y = v.y > 0.f ? v.y : 0.01f * v.y;
        v.z = v.z > 0.f ? v.z : 0.01f * v.z;
        v.w = v.w > 0.f ? v.w : 0.01f * v.w;
        ((float4*)out)[i] = v;
    }
}

extern "C" void kernel_launch(void* const* d_in, const int* in_sizes, int n_in,
                              void* d_out, int out_size, void* d_ws, size_t ws_size,
                              hipStream_t stream) {
    const float* src_x = (const float*)d_in[0];
    const float* dst_x = (const float*)d_in[1];
    const int*   eidx  = (const int*)d_in[2];     // [2, E] flat: src then dst
    const float* ew    = (const float*)d_in[3];   // [E, 1]
    const float* Wi    = (const float*)d_in[4];   // [D, D]
    const float* We    = (const float*)d_in[5];   // [D, D]
    float* out = (float*)d_out;

    // ws layout
    char* wsb = (char*)d_ws;
    unsigned short* Wfi    = (unsigned short*)(wsb);                    // 32768 B
    unsigned short* Wfe    = (unsigned short*)(wsb + 32768);            // 32768 B
    unsigned short* src_bf = (unsigned short*)(wsb + 65536);            // 25.6 MB
    unsigned short* dst_bf = src_bf + (size_t)N_NODES * D;              // 25.6 MB
    char* p = (char*)(dst_bf + (size_t)N_NODES * D);
    int*      sIp  = (int*)p;                 p += (size_t)N_EDGES * 4;
    int*      dIp  = (int*)p;                 p += (size_t)N_EDGES * 4;
    float*    ewp  = (float*)p;               p += (size_t)N_EDGES * 4;
    unsigned* cnt  = (unsigned*)p;            p += (size_t)(NBLK * SCAN_B) * 4;
    unsigned* off  = (unsigned*)p;            p += (size_t)(NBLK * SCAN_B) * 4;
    unsigned* bsum = (unsigned*)p;

    const int* src_idx = eidx;
    const int* dst_idx = eidx + N_EDGES;

    wfrag_kernel<<<16, 256, 0, stream>>>(Wi, We, Wfi, Wfe);

    int n4 = N_NODES * D / 4;
    cvt2_kernel<<<(2 * n4 + 255) / 256, 256, 0, stream>>>(src_x, dst_x,
                                                          src_bf, dst_bf, n4);

    // --- dst-sort preprocessing
    hipMemsetAsync(cnt, 0, (size_t)N_NODES * 4, stream);
    hist_kernel<<<(N_EDGES + 255) / 256, 256, 0, stream>>>(dst_idx, cnt);
    scanA_kernel<<<NBLK, SCAN_B, 0, stream>>>(cnt, off, bsum);
    scanB_kernel<<<1, 256, 0, stream>>>(bsum);
    scanC_kernel<<<(N_NODES + 255) / 256, 256, 0, stream>>>(off, bsum);
    scatter_kernel<<<(N_EDGES + 255) / 256, 256, 0, stream>>>(
        src_idx, dst_idx, ew, off, sIp, dIp, ewp);

    node_mfma2_kernel<<<N_NODES / (16 * NG_N), 256, 0, stream>>>(dst_bf, Wfi, out);

    edge_mfma4_kernel<<<N_EDGES / (16 * NG_E), 256, 0, stream>>>(
        src_bf, dst_bf, sIp, dIp, ewp, Wfi, Wfe, out);

    leaky_relu4_kernel<<<(n4 + 255) / 256, 256, 0, stream>>>(out, n4);
}

// Round 8
// 405.246 us; speedup vs baseline: 1.0978x; 1.0978x over previous
//
#include <hip/hip_runtime.h>
#include <hip/hip_bf16.h>

#define N_NODES 100000
#define N_EDGES 600000
#define D 128
#define NG_E 12   // 16-edge groups per block: 192 edges/block, 3125 blocks
#define NG_N 10   // 16-row  groups per block: 625 blocks
#define SCAN_B 512
#define NBLK ((N_NODES + SCAN_B - 1) / SCAN_B)   // 196

typedef __attribute__((ext_vector_type(8))) short short8;
typedef __attribute__((ext_vector_type(8))) unsigned short ushort8;
typedef __attribute__((ext_vector_type(4))) unsigned int uint4v;
typedef __attribute__((ext_vector_type(4))) float f32x4;

union V8 { short8 s8; ushort8 u8; uint4v u4; };

__device__ __forceinline__ unsigned short f2bf(float f) {
    unsigned u = __float_as_uint(f);
    u += 0x7FFF + ((u >> 16) & 1);   // RNE
    return (unsigned short)(u >> 16);
}

// ---------------- weight fragments ----------------
__global__ void wfrag_kernel(const float* __restrict__ Wi,
                             const float* __restrict__ We,
                             unsigned short* __restrict__ Wfi,
                             unsigned short* __restrict__ Wfe) {
    int id = blockIdx.x * blockDim.x + threadIdx.x;   // 0..4095
    int mat = id >> 11;
    int idx = id & 2047;          // nt<<8 | ks<<6 | lane
    int lane = idx & 63;
    int ks = (idx >> 6) & 3;
    int nt = idx >> 8;
    int n = lane & 15, quad = lane >> 4;
    int row = nt * 16 + n;
    int k0 = ks * 32 + quad * 8;
    const float* W = mat ? We : Wi;
    unsigned short* Wf = mat ? Wfe : Wfi;
    #pragma unroll
    for (int j = 0; j < 8; ++j)
        Wf[idx * 8 + j] = f2bf(W[row * D + k0 + j]);
}

// src_x -> src_bf only (dst conversion is fused into the node kernel)
__global__ void cvt_kernel(const float* __restrict__ x,
                           unsigned short* __restrict__ xb, int n4) {
    int i = blockIdx.x * blockDim.x + threadIdx.x;
    if (i < n4) {
        float4 v = ((const float4*)x)[i];
        ushort4 o;
        o.x = f2bf(v.x); o.y = f2bf(v.y); o.z = f2bf(v.z); o.w = f2bf(v.w);
        ((ushort4*)xb)[i] = o;
    }
}

// ---------------- dst-sort preprocessing (CSR order) ----------------
__global__ void hist_kernel(const int* __restrict__ dst_idx,
                            unsigned* __restrict__ cnt) {
    int i = blockIdx.x * blockDim.x + threadIdx.x;
    if (i < N_EDGES) atomicAdd(&cnt[dst_idx[i]], 1u);
}

// per-block exclusive scan of cnt -> off (block-local), block totals -> bsum
__global__ __launch_bounds__(SCAN_B) void scanA_kernel(
    const unsigned* __restrict__ cnt, unsigned* __restrict__ off,
    unsigned* __restrict__ bsum) {
    int b = blockIdx.x, t = threadIdx.x;
    int i = b * SCAN_B + t;
    unsigned x = (i < N_NODES) ? cnt[i] : 0u;
    unsigned v = x;
    #pragma unroll
    for (int o = 1; o < 64; o <<= 1) {
        unsigned u = __shfl_up(v, o);
        if ((t & 63) >= o) v += u;
    }
    __shared__ unsigned wsum[SCAN_B / 64];
    if ((t & 63) == 63) wsum[t >> 6] = v;
    __syncthreads();
    if (t < SCAN_B / 64) {
        unsigned s = wsum[t];
        unsigned vv = s;
        #pragma unroll
        for (int o = 1; o < SCAN_B / 64; o <<= 1) {
            unsigned u = __shfl_up(vv, o);
            if (t >= o) vv += u;
        }
        wsum[t] = vv - s;   // exclusive wave offset
    }
    __syncthreads();
    unsigned inc = v + wsum[t >> 6];
    if (i < N_NODES) off[i] = inc - x;   // block-local exclusive
    if (t == SCAN_B - 1) bsum[b] = inc;
}

// single block: exclusive scan of bsum (NBLK <= 256)
__global__ __launch_bounds__(256) void scanB_kernel(unsigned* __restrict__ bsum) {
    int t = threadIdx.x;
    unsigned x = (t < NBLK) ? bsum[t] : 0u;
    unsigned v = x;
    #pragma unroll
    for (int o = 1; o < 64; o <<= 1) {
        unsigned u = __shfl_up(v, o);
        if ((t & 63) >= o) v += u;
    }
    __shared__ unsigned wsum[4];
    if ((t & 63) == 63) wsum[t >> 6] = v;
    __syncthreads();
    if (t < 4) {
        unsigned s = wsum[t];
        unsigned vv = s;
        #pragma unroll
        for (int o = 1; o < 4; o <<= 1) {
            unsigned u = __shfl_up(vv, o);
            if (t >= o) vv += u;
        }
        wsum[t] = vv - s;
    }
    __syncthreads();
    unsigned inc = v + wsum[t >> 6];
    if (t < NBLK) bsum[t] = inc - x;   // exclusive
}

// scatter edges into dst-sorted order; off is block-local cursor, bsum adds
// the global block offset (scanC folded in here).
__global__ void scatter_kernel(const int* __restrict__ src_idx,
                               const int* __restrict__ dst_idx,
                               const float* __restrict__ ew,
                               unsigned* __restrict__ off,
                               const unsigned* __restrict__ bsum,
                               int* __restrict__ sIp, int* __restrict__ dIp,
                               float* __restrict__ ewp) {
    int i = blockIdx.x * blockDim.x + threadIdx.x;
    if (i < N_EDGES) {
        int d = dst_idx[i];
        unsigned pos = atomicAdd(&off[d], 1u) + bsum[d / SCAN_B];
        sIp[pos] = src_idx[i];
        dIp[pos] = d;
        ewp[pos] = ew[i];
    }
}

// ---------------- node self-message (+ fused dst bf16 conversion) ----------
__global__ __launch_bounds__(256, 4) void node_mfma3_kernel(
    const float* __restrict__ dst_x,
    const unsigned short* __restrict__ Wfi,
    unsigned short* __restrict__ dst_bf, float* __restrict__ out) {
    int t = threadIdx.x, lane = t & 63, w = t >> 6;
    int quad = lane >> 4, nl = lane & 15;
    const short8* Wv = (const short8*)Wfi;
    short8 Bf[2][4];
    #pragma unroll
    for (int ntl = 0; ntl < 2; ++ntl)
        #pragma unroll
        for (int ks = 0; ks < 4; ++ks)
            Bf[ntl][ks] = Wv[((2 * w + ntl) * 4 + ks) * 64 + lane];

    int base = blockIdx.x * (NG_N * 16);
    for (int g = 0; g < NG_N; ++g) {
        int gbase = base + g * 16;
        const float* xr = dst_x + (size_t)(gbase + nl) * D + quad * 8;
        unsigned short* br = dst_bf + (size_t)(gbase + nl) * D + quad * 8;
        f32x4 acc[2];
        acc[0] = (f32x4){0.f, 0.f, 0.f, 0.f};
        acc[1] = (f32x4){0.f, 0.f, 0.f, 0.f};
        #pragma unroll
        for (int ks = 0; ks < 4; ++ks) {
            float4 f0 = *(const float4*)(xr + ks * 32);
            float4 f1 = *(const float4*)(xr + ks * 32 + 4);
            V8 a;
            a.u8[0] = f2bf(f0.x); a.u8[1] = f2bf(f0.y);
            a.u8[2] = f2bf(f0.z); a.u8[3] = f2bf(f0.w);
            a.u8[4] = f2bf(f1.x); a.u8[5] = f2bf(f1.y);
            a.u8[6] = f2bf(f1.z); a.u8[7] = f2bf(f1.w);
            *(ushort8*)(br + ks * 32) = a.u8;   // side product for edge kernel
            acc[0] = __builtin_amdgcn_mfma_f32_16x16x32_bf16(a.s8, Bf[0][ks], acc[0], 0, 0, 0);
            acc[1] = __builtin_amdgcn_mfma_f32_16x16x32_bf16(a.s8, Bf[1][ks], acc[1], 0, 0, 0);
        }
        #pragma unroll
        for (int ntl = 0; ntl < 2; ++ntl)
            #pragma unroll
            for (int r = 0; r < 4; ++r)
                out[(size_t)(gbase + quad * 4 + r) * D + (2 * w + ntl) * 16 + nl]
                    = acc[ntl][r];
    }
}

// ---------------- fused edge GEMM over dst-sorted edges ----------------
// Quad q owns the contiguous edge span [q*48, (q+1)*48) of the block's 192
// sorted edges (row m of group g <-> edge (m>>2)*48 + g*4 + (m&3)), so runs
// carry across groups: flush atomics only when dst changes.
__global__ __launch_bounds__(256, 2) void edge_mfma5_kernel(
    const unsigned short* __restrict__ src_bf,
    const unsigned short* __restrict__ dst_bf,
    const int* __restrict__ sIp, const int* __restrict__ dIp,
    const float* __restrict__ ewp,
    const unsigned short* __restrict__ Wfi,
    const unsigned short* __restrict__ Wfe,
    float* __restrict__ out) {
    int t = threadIdx.x, lane = t & 63, w = t >> 6;
    int quad = lane >> 4, nl = lane & 15;
    const short8* Wiv = (const short8*)Wfi;
    const short8* Wev = (const short8*)Wfe;
    short8 Bi[2][4], Be[2][4];
    #pragma unroll
    for (int ntl = 0; ntl < 2; ++ntl)
        #pragma unroll
        for (int ks = 0; ks < 4; ++ks) {
            Bi[ntl][ks] = Wiv[((2 * w + ntl) * 4 + ks) * 64 + lane];
            Be[ntl][ks] = Wev[((2 * w + ntl) * 4 + ks) * 64 + lane];
        }

    int base = blockIdx.x * (NG_E * 16);

    // chunk c regs: lane l holds edge base + (l>>4)*48 + c*16 + (l&15)
    int ce0 = base + (lane >> 4) * 48 + (lane & 15);
    int sC = sIp[ce0];
    int dC = dIp[ce0];
    float eC = ewp[ce0];

    V8 sv[2][4], dv[2][4];

    {   // prefetch group 0 (gi=0): A-row nl <- chunk lane (nl>>2)*16 + (nl&3)
        int slsrc = ((nl >> 2) << 4) | (nl & 3);
        int sl = __shfl(sC, slsrc);
        int tl = __shfl(dC, slsrc);
        const unsigned short* sp = src_bf + (size_t)sl * D + quad * 8;
        const unsigned short* dp = dst_bf + (size_t)tl * D + quad * 8;
        #pragma unroll
        for (int ks = 0; ks < 4; ++ks) {
            sv[0][ks].u8 = *(const ushort8*)(sp + ks * 32);
            dv[0][ks].u8 = *(const ushort8*)(dp + ks * 32);
        }
    }

    int run_dst = -1;
    float run0 = 0.f, run1 = 0.f;
    const int c0 = (2 * w) * 16 + nl, c1 = (2 * w + 1) * 16 + nl;

    #pragma unroll
    for (int g = 0; g < NG_E; ++g) {
        const int buf = g & 1, nbuf = buf ^ 1;
        int sN = sC, dN = dC;
        float eN = eC;
        bool roll = false;

        // --- issue next group's gathers first
        if (g + 1 < NG_E) {
            const int gn = g + 1, gin = gn & 3;
            if (gin == 0) {          // new 16-edges-per-quad chunk
                int ce = base + (lane >> 4) * 48 + (gn >> 2) * 16 + (lane & 15);
                sN = sIp[ce];
                dN = dIp[ce];
                eN = ewp[ce];
                roll = true;
            }
            int slsrc = ((nl >> 2) << 4) | (gin << 2) | (nl & 3);
            int sl = __shfl(roll ? sN : sC, slsrc);
            int tl = __shfl(roll ? dN : dC, slsrc);
            const unsigned short* sp = src_bf + (size_t)sl * D + quad * 8;
            const unsigned short* dp = dst_bf + (size_t)tl * D + quad * 8;
            #pragma unroll
            for (int ks = 0; ks < 4; ++ks) {
                sv[nbuf][ks].u8 = *(const ushort8*)(sp + ks * 32);
                dv[nbuf][ks].u8 = *(const ushort8*)(dp + ks * 32);
            }
        }

        // --- compute current group
        f32x4 acc[2];
        acc[0] = (f32x4){0.f, 0.f, 0.f, 0.f};
        acc[1] = (f32x4){0.f, 0.f, 0.f, 0.f};
        #pragma unroll
        for (int ks = 0; ks < 4; ++ks) {
            V8 pU;
            #pragma unroll
            for (int h = 0; h < 4; ++h) {
                unsigned su = sv[buf][ks].u4[h], du = dv[buf][ks].u4[h];
                float p0 = __uint_as_float(su << 16) * __uint_as_float(du << 16);
                float p1 = __uint_as_float(su & 0xFFFF0000u) *
                           __uint_as_float(du & 0xFFFF0000u);
                __hip_bfloat162 h2 = __float22bfloat162_rn(make_float2(p0, p1));
                pU.u4[h] = *(unsigned*)&h2;
            }
            short8 a1 = sv[buf][ks].s8, a2 = pU.s8;
            acc[0] = __builtin_amdgcn_mfma_f32_16x16x32_bf16(a1, Bi[0][ks], acc[0], 0, 0, 0);
            acc[1] = __builtin_amdgcn_mfma_f32_16x16x32_bf16(a1, Bi[1][ks], acc[1], 0, 0, 0);
            acc[0] = __builtin_amdgcn_mfma_f32_16x16x32_bf16(a2, Be[0][ks], acc[0], 0, 0, 0);
            acc[1] = __builtin_amdgcn_mfma_f32_16x16x32_bf16(a2, Be[1][ks], acc[1], 0, 0, 0);
        }

        // --- epilogue: carried segmented reduction; C row quad*4+r is edge
        //     quad*48 + g*4 + r  <->  chunk lane quad*16 + gi*4 + r
        const int gi = g & 3;
        #pragma unroll
        for (int r = 0; r < 4; ++r) {
            int sl = (quad << 4) | (gi << 2) | r;
            int dr = __shfl(dC, sl);
            float wm = __shfl(eC, sl);
            if (dr == run_dst) {
                run0 += wm * acc[0][r];
                run1 += wm * acc[1][r];
            } else {
                if (run_dst >= 0) {
                    float* orow = out + (size_t)run_dst * D;
                    atomicAdd(orow + c0, run0);
                    atomicAdd(orow + c1, run1);
                }
                run_dst = dr;
                run0 = wm * acc[0][r];
                run1 = wm * acc[1][r];
            }
        }

        if (roll) { sC = sN; dC = dN; eC = eN; }
    }

    {   // final flush
        float* orow = out + (size_t)run_dst * D;
        atomicAdd(orow + c0, run0);
        atomicAdd(orow + c1, run1);
    }
}

__global__ void leaky_relu4_kernel(float* __restrict__ out, int n4) {
    int i = blockIdx.x * blockDim.x + threadIdx.x;
    if (i < n4) {
        float4 v = ((const float4*)out)[i];
        v.x = v.x > 0.f ? v.x : 0.01f * v.x;
        v.y = v.y > 0.f ? v.y : 0.01f * v.y;
        v.z = v.z > 0.f ? v.z : 0.01f * v.z;
        v.w = v.w > 0.f ? v.w : 0.01f * v.w;
        ((float4*)out)[i] = v;
    }
}

extern "C" void kernel_launch(void* const* d_in, const int* in_sizes, int n_in,
                              void* d_out, int out_size, void* d_ws, size_t ws_size,
                              hipStream_t stream) {
    const float* src_x = (const float*)d_in[0];
    const float* dst_x = (const float*)d_in[1];
    const int*   eidx  = (const int*)d_in[2];     // [2, E] flat: src then dst
    const float* ew    = (const float*)d_in[3];   // [E, 1]
    const float* Wi    = (const float*)d_in[4];   // [D, D]
    const float* We    = (const float*)d_in[5];   // [D, D]
    float* out = (float*)d_out;

    // ws layout
    char* wsb = (char*)d_ws;
    unsigned short* Wfi    = (unsigned short*)(wsb);                    // 32768 B
    unsigned short* Wfe    = (unsigned short*)(wsb + 32768);            // 32768 B
    unsigned short* src_bf = (unsigned short*)(wsb + 65536);            // 25.6 MB
    unsigned short* dst_bf = src_bf + (size_t)N_NODES * D;              // 25.6 MB
    char* p = (char*)(dst_bf + (size_t)N_NODES * D);
    int*      sIp  = (int*)p;                 p += (size_t)N_EDGES * 4;
    int*      dIp  = (int*)p;                 p += (size_t)N_EDGES * 4;
    float*    ewp  = (float*)p;               p += (size_t)N_EDGES * 4;
    unsigned* cnt  = (unsigned*)p;            p += (size_t)(NBLK * SCAN_B) * 4;
    unsigned* off  = (unsigned*)p;            p += (size_t)(NBLK * SCAN_B) * 4;
    unsigned* bsum = (unsigned*)p;

    const int* src_idx = eidx;
    const int* dst_idx = eidx + N_EDGES;

    wfrag_kernel<<<16, 256, 0, stream>>>(Wi, We, Wfi, Wfe);

    int n4 = N_NODES * D / 4;
    cvt_kernel<<<(n4 + 255) / 256, 256, 0, stream>>>(src_x, src_bf, n4);

    // --- dst-sort preprocessing
    hipMemsetAsync(cnt, 0, (size_t)N_NODES * 4, stream);
    hist_kernel<<<(N_EDGES + 255) / 256, 256, 0, stream>>>(dst_idx, cnt);
    scanA_kernel<<<NBLK, SCAN_B, 0, stream>>>(cnt, off, bsum);
    scanB_kernel<<<1, 256, 0, stream>>>(bsum);
    scatter_kernel<<<(N_EDGES + 255) / 256, 256, 0, stream>>>(
        src_idx, dst_idx, ew, off, bsum, sIp, dIp, ewp);

    node_mfma3_kernel<<<N_NODES / (16 * NG_N), 256, 0, stream>>>(dst_x, Wfi,
                                                                 dst_bf, out);

    edge_mfma5_kernel<<<N_EDGES / (16 * NG_E), 256, 0, stream>>>(
        src_bf, dst_bf, sIp, dIp, ewp, Wfi, Wfe, out);

    leaky_relu4_kernel<<<(n4 + 255) / 256, 256, 0, stream>>>(out, n4);
}